// Round 2
// baseline (1163.801 us; speedup 1.0000x reference)
//
#include <hip/hip_runtime.h>

#define N 65536
#define D 64
#define V 8192
#define LOSS_OFF (N * D)
#define IDX_OFF (N * D + 1)
#define MARGIN 0.04f

typedef _Float16 half8 __attribute__((ext_vector_type(8)));
typedef float f32x4 __attribute__((ext_vector_type(4)));

typedef __attribute__((address_space(1))) const void gas_t;
typedef __attribute__((address_space(3))) void las_t;

// ---------------- kernel 1: Ef16 = f16(-2E), e2 = sum E^2 (exact f32) -------
__global__ void k_split(const float* __restrict__ E, _Float16* __restrict__ Ef16,
                        float* __restrict__ e2, float* __restrict__ dout) {
    int v = blockIdx.x * 256 + threadIdx.x;
    if (v == 0) dout[LOSS_OFF] = 0.0f;
    if (v >= V) return;
    const float4* row = (const float4*)(E + (size_t)v * D);
    float s = 0.0f;
#pragma unroll
    for (int i = 0; i < 16; ++i) {
        float4 t = row[i];
        s += t.x * t.x + t.y * t.y + t.z * t.z + t.w * t.w;
        half8* hp = (half8*)(Ef16 + (size_t)v * D + i * 4);
        // pack 4 at a time: write two float4->half4 pairs per half8 slot
        // simpler: accumulate into local then store below
    }
    e2[v] = s;
    // write Ef16 row: 8 x half8
#pragma unroll
    for (int i = 0; i < 8; ++i) {
        float4 lo = row[i * 2];
        float4 hi = row[i * 2 + 1];
        half8 h;
        h[0] = (_Float16)(-2.0f * lo.x); h[1] = (_Float16)(-2.0f * lo.y);
        h[2] = (_Float16)(-2.0f * lo.z); h[3] = (_Float16)(-2.0f * lo.w);
        h[4] = (_Float16)(-2.0f * hi.x); h[5] = (_Float16)(-2.0f * hi.y);
        h[6] = (_Float16)(-2.0f * hi.z); h[7] = (_Float16)(-2.0f * hi.w);
        *(half8*)(Ef16 + (size_t)v * D + i * 8) = h;
    }
}

// ---------------- kernel 2: MFMA approx argmin (group granularity 32) -------
// block: 512 thr = 8 waves, each wave owns 32 rows (2 row-frags of 16).
// sweep V in chunks of 128 cols; per chunk 4 col-block-pairs.
__global__ __launch_bounds__(512) void k_argmin(const float* __restrict__ X,
                                                const _Float16* __restrict__ Ef16,
                                                const float* __restrict__ e2,
                                                unsigned* __restrict__ gidw) {
    __shared__ __align__(16) _Float16 els[2][8192];  // 2 x 16KB, swizzled
    __shared__ __align__(16) float e2ls[2][128];

    const int tid = threadIdx.x;
    const int lane = tid & 63;
    const int wave = tid >> 6;
    const int c4 = lane & 15;
    const int kg = lane >> 4;  // 0..3
    const int wrow = blockIdx.x * 256 + wave * 32;

    // ---- A frags: load X rows, convert f32->f16 in-register ----
    half8 a[2][2];
#pragma unroll
    for (int rf = 0; rf < 2; ++rf) {
        const float* xrow = X + (size_t)(wrow + rf * 16 + c4) * D;
#pragma unroll
        for (int f = 0; f < 2; ++f) {
            float4 lo = *(const float4*)(xrow + f * 32 + kg * 8);
            float4 hi = *(const float4*)(xrow + f * 32 + kg * 8 + 4);
            half8 h;
            h[0] = (_Float16)lo.x; h[1] = (_Float16)lo.y;
            h[2] = (_Float16)lo.z; h[3] = (_Float16)lo.w;
            h[4] = (_Float16)hi.x; h[5] = (_Float16)hi.y;
            h[6] = (_Float16)hi.z; h[7] = (_Float16)hi.w;
            a[rf][f] = h;
        }
    }

    float m1[2][4], m2[2][4];
    unsigned gid[2][4];
#pragma unroll
    for (int rf = 0; rf < 2; ++rf)
#pragma unroll
        for (int r = 0; r < 4; ++r) {
            m1[rf][r] = 3.4e38f;
            m2[rf][r] = 3.4e38f;
            gid[rf][r] = 0;
        }

    // ---- staging helper (as a lambda-free macro) ----
    // LDS chunk layout: row c (0..127) = 128B = 8 x 16B subchunks; subchunk
    // position p holds original subchunk j = p ^ (c&7)  (bank-spread swizzle).
    // global_load_lds: linear LDS dest, pre-swizzled global source (m173).
#define STAGE(BUF, CH)                                                        \
    {                                                                         \
        _Pragma("unroll") for (int it = 0; it < 2; ++it) {                    \
            int q = it * 512 + tid; /* 16B chunk index 0..1023 */             \
            int c = q >> 3, p = q & 7, j = p ^ (c & 7);                       \
            const _Float16* src =                                             \
                Ef16 + ((size_t)((CH)*128 + c) * D + j * 8);                  \
            __builtin_amdgcn_global_load_lds((gas_t*)src,                     \
                                             (las_t*)&els[BUF][q * 8], 16, 0, \
                                             0);                              \
        }                                                                     \
        if (tid < 32) {                                                       \
            const float* s2 = e2 + (CH)*128 + tid * 4;                        \
            __builtin_amdgcn_global_load_lds(                                 \
                (gas_t*)s2, (las_t*)&e2ls[BUF][tid * 4], 16, 0, 0);           \
        }                                                                     \
    }

    STAGE(0, 0)

    for (int ch = 0; ch < 64; ++ch) {
        __syncthreads();  // drains vmcnt of prior STAGE; buf ready
        if (ch < 63) STAGE((ch + 1) & 1, ch + 1)
        const int buf = ch & 1;

#pragma unroll
        for (int pb = 0; pb < 4; ++pb) {
            // B frags for the two 16-col blocks of this pair
            const int c0 = pb * 32 + c4;        // col-block 0 row-in-chunk
            const int c1 = pb * 32 + 16 + c4;   // col-block 1
            const int sw = c4 & 7;
            half8 b00 = *(const half8*)&els[buf][c0 * 64 + ((0 + kg) ^ sw) * 8];
            half8 b01 = *(const half8*)&els[buf][c0 * 64 + ((4 + kg) ^ sw) * 8];
            half8 b10 = *(const half8*)&els[buf][c1 * 64 + ((0 + kg) ^ sw) * 8];
            half8 b11 = *(const half8*)&els[buf][c1 * 64 + ((4 + kg) ^ sw) * 8];
            float e2v0 = e2ls[buf][pb * 32 + c4];
            float e2v1 = e2ls[buf][pb * 32 + 16 + c4];
            f32x4 i0 = {e2v0, e2v0, e2v0, e2v0};
            f32x4 i1 = {e2v1, e2v1, e2v1, e2v1};

            f32x4 acc[2][2];
#pragma unroll
            for (int rf = 0; rf < 2; ++rf) {
                f32x4 t0 = __builtin_amdgcn_mfma_f32_16x16x32_f16(a[rf][0], b00, i0, 0, 0, 0);
                acc[rf][0] = __builtin_amdgcn_mfma_f32_16x16x32_f16(a[rf][1], b01, t0, 0, 0, 0);
                f32x4 t1 = __builtin_amdgcn_mfma_f32_16x16x32_f16(a[rf][0], b10, i1, 0, 0, 0);
                acc[rf][1] = __builtin_amdgcn_mfma_f32_16x16x32_f16(a[rf][1], b11, t1, 0, 0, 0);
            }

            const unsigned pid = (unsigned)(ch * 4 + pb);
#pragma unroll
            for (int rf = 0; rf < 2; ++rf)
#pragma unroll
                for (int r = 0; r < 4; ++r) {
                    float v0 = acc[rf][0][r], v1 = acc[rf][1][r];
                    float a1 = fminf(v0, v1);
                    float a2 = fmaxf(v0, v1);
                    float om1 = m1[rf][r];
                    m2[rf][r] = fminf(fminf(fmaxf(om1, a1), m2[rf][r]), a2);
                    if (a1 < om1) gid[rf][r] = pid;
                    m1[rf][r] = fminf(om1, a1);
                }
        }
    }

    // ---- cross-lane top-2 merge over the 16 column lanes ----
#pragma unroll
    for (int rf = 0; rf < 2; ++rf)
#pragma unroll
        for (int r = 0; r < 4; ++r) {
            float v1 = m1[rf][r], v2 = m2[rf][r];
            unsigned g = gid[rf][r];
#pragma unroll
            for (int off = 1; off < 16; off <<= 1) {
                float o1 = __shfl_xor(v1, off, 16);
                float o2 = __shfl_xor(v2, off, 16);
                unsigned og = __shfl_xor((int)g, off, 16);
                v2 = fminf(fminf(fmaxf(v1, o1), v2), o2);
                if (o1 < v1) { g = og; }
                v1 = fminf(v1, o1);
            }
            if (c4 == 0) {
                int row = wrow + rf * 16 + kg * 4 + r;
                unsigned flag = (v2 - v1 < MARGIN) ? 1u : 0u;
                gidw[row] = (g << 1) | flag;
            }
        }
}

// ---------------- kernel 3: exact f32 recovery ------------------------------
// one wave per row. unflagged: exact scan of winning 32-entry group.
// flagged: exact scan of all 8192 entries. ties -> lowest index (ref match).
__global__ __launch_bounds__(256) void k_recover(const float* __restrict__ X,
                                                 const float* __restrict__ E,
                                                 const float* __restrict__ e2,
                                                 const unsigned* __restrict__ gidw,
                                                 float* __restrict__ dout) {
    const int tid = threadIdx.x;
    const int lane = tid & 63;
    const int row = blockIdx.x * 4 + (tid >> 6);
    const unsigned g = gidw[row];
    const bool flag = g & 1;

    float4 xr[16];
    const float4* xp = (const float4*)(X + (size_t)row * D);
#pragma unroll
    for (int i = 0; i < 16; ++i) xr[i] = xp[i];

    float best = 3.4e38f;
    int bidx = 0x7fffffff;
    int v, cnt, stride;
    if (flag) {
        v = lane; cnt = V / 64; stride = 64;
    } else {
        v = (int)(g >> 1) * 32 + lane; cnt = (lane < 32) ? 1 : 0; stride = 0;
    }
    for (int e = 0; e < cnt; ++e, v += stride) {
        const float4* ep = (const float4*)(E + (size_t)v * D);
        float s = 0.0f;
#pragma unroll
        for (int i = 0; i < 16; ++i) {
            float4 a = xr[i];
            float4 b = ep[i];
            s = fmaf(a.x, b.x, s); s = fmaf(a.y, b.y, s);
            s = fmaf(a.z, b.z, s); s = fmaf(a.w, b.w, s);
        }
        float d = fmaf(-2.0f, s, e2[v]);
        if (d < best) { best = d; bidx = v; }  // strict <: lowest idx on ties
    }
#pragma unroll
    for (int off = 32; off; off >>= 1) {
        float ob = __shfl_xor(best, off, 64);
        int oi = __shfl_xor(bidx, off, 64);
        if (ob < best || (ob == best && oi < bidx)) { best = ob; bidx = oi; }
    }
    if (lane == 0) dout[IDX_OFF + row] = (float)bidx;
}

// ---------------- kernel 4: gather + STE output + loss ----------------------
__global__ void k_out(const float* __restrict__ X, const float* __restrict__ E,
                      float* __restrict__ dout) {
    const int t = blockIdx.x * 256 + threadIdx.x;
    const int n = t >> 4;
    const int d = (t & 15) * 4;
    const int idx = (int)dout[IDX_OFF + n];
    float4 x4 = *(const float4*)(X + (size_t)n * D + d);
    float4 q4 = *(const float4*)(E + (size_t)idx * D + d);
    float4 o;
    o.x = x4.x + (q4.x - x4.x);
    o.y = x4.y + (q4.y - x4.y);
    o.z = x4.z + (q4.z - x4.z);
    o.w = x4.w + (q4.w - x4.w);
    *(float4*)(dout + (size_t)n * D + d) = o;

    float dx = q4.x - x4.x, dy = q4.y - x4.y, dz = q4.z - x4.z,
          dw = q4.w - x4.w;
    float s = dx * dx + dy * dy + dz * dz + dw * dw;
#pragma unroll
    for (int off = 32; off; off >>= 1) s += __shfl_down(s, off, 64);
    __shared__ float ps[4];
    if ((threadIdx.x & 63) == 0) ps[threadIdx.x >> 6] = s;
    __syncthreads();
    if (threadIdx.x == 0) {
        float tot = ps[0] + ps[1] + ps[2] + ps[3];
        atomicAdd(dout + LOSS_OFF, tot * (1.25f / ((float)N * (float)D)));
    }
}

extern "C" void kernel_launch(void* const* d_in, const int* in_sizes, int n_in,
                              void* d_out, int out_size, void* d_ws,
                              size_t ws_size, hipStream_t stream) {
    const float* X = (const float*)d_in[0];
    const float* E = (const float*)d_in[1];
    float* out = (float*)d_out;

    _Float16* Ef16 = (_Float16*)d_ws;                                  // 1 MB
    float* e2 = (float*)((char*)d_ws + (1 << 20));                     // 32 KB
    unsigned* gidw = (unsigned*)((char*)d_ws + (1 << 20) + (32 << 10)); // 256 KB

    k_split<<<V / 256, 256, 0, stream>>>(E, Ef16, e2, out);
    k_argmin<<<N / 256, 512, 0, stream>>>(X, Ef16, e2, gidw);
    k_recover<<<N / 4, 256, 0, stream>>>(X, E, e2, gidw, out);
    k_out<<<(N * 16) / 256, 256, 0, stream>>>(X, E, out);
}

// Round 3
// 424.889 us; speedup vs baseline: 2.7391x; 2.7391x over previous
//
#include <hip/hip_runtime.h>

#define N 65536
#define D 64
#define V 8192
#define LOSS_OFF (N * D)
#define IDX_OFF (N * D + 1)
#define MARGIN 0.02f

typedef _Float16 half8 __attribute__((ext_vector_type(8)));
typedef float f32x4 __attribute__((ext_vector_type(4)));

typedef __attribute__((address_space(1))) const void gas_t;
typedef __attribute__((address_space(3))) void las_t;

// 16-dim partial dot with named float4 regs (never an indexed array -> no scratch)
#define DOT16(s, A0, A1, A2, A3, B0, B1, B2, B3)                         \
    s = fmaf(A0.x, B0.x, s); s = fmaf(A0.y, B0.y, s);                    \
    s = fmaf(A0.z, B0.z, s); s = fmaf(A0.w, B0.w, s);                    \
    s = fmaf(A1.x, B1.x, s); s = fmaf(A1.y, B1.y, s);                    \
    s = fmaf(A1.z, B1.z, s); s = fmaf(A1.w, B1.w, s);                    \
    s = fmaf(A2.x, B2.x, s); s = fmaf(A2.y, B2.y, s);                    \
    s = fmaf(A2.z, B2.z, s); s = fmaf(A2.w, B2.w, s);                    \
    s = fmaf(A3.x, B3.x, s); s = fmaf(A3.y, B3.y, s);                    \
    s = fmaf(A3.z, B3.z, s); s = fmaf(A3.w, B3.w, s);

// ---------------- kernel 1: Ef16 = f16(-2E), e2 = sum E^2, zero scalars -----
__global__ void k_split(const float* __restrict__ E, _Float16* __restrict__ Ef16,
                        float* __restrict__ e2, float* __restrict__ dout,
                        int* __restrict__ fcount) {
    int v = blockIdx.x * 256 + threadIdx.x;
    if (v == 0) {
        dout[LOSS_OFF] = 0.0f;
        *fcount = 0;
    }
    if (v >= V) return;
    const float4* row = (const float4*)(E + (size_t)v * D);
    float s = 0.0f;
#pragma unroll
    for (int i = 0; i < 16; ++i) {
        float4 t = row[i];
        s += t.x * t.x + t.y * t.y + t.z * t.z + t.w * t.w;
    }
    e2[v] = s;
#pragma unroll
    for (int i = 0; i < 8; ++i) {
        float4 lo = row[i * 2];
        float4 hi = row[i * 2 + 1];
        half8 h;
        h[0] = (_Float16)(-2.0f * lo.x); h[1] = (_Float16)(-2.0f * lo.y);
        h[2] = (_Float16)(-2.0f * lo.z); h[3] = (_Float16)(-2.0f * lo.w);
        h[4] = (_Float16)(-2.0f * hi.x); h[5] = (_Float16)(-2.0f * hi.y);
        h[6] = (_Float16)(-2.0f * hi.z); h[7] = (_Float16)(-2.0f * hi.w);
        *(half8*)(Ef16 + (size_t)v * D + i * 8) = h;
    }
}

// ---------------- kernel 2: MFMA approx argmin + flagged-row compaction -----
__global__ __launch_bounds__(512) void k_argmin(const float* __restrict__ X,
                                                const _Float16* __restrict__ Ef16,
                                                const float* __restrict__ e2,
                                                unsigned* __restrict__ gidw,
                                                int* __restrict__ fcount,
                                                int* __restrict__ flist) {
    __shared__ __align__(16) _Float16 els[2][8192];  // 2 x 16KB, swizzled
    __shared__ __align__(16) float e2ls[2][128];

    const int tid = threadIdx.x;
    const int lane = tid & 63;
    const int wave = tid >> 6;
    const int c4 = lane & 15;
    const int kg = lane >> 4;  // 0..3
    const int wrow = blockIdx.x * 256 + wave * 32;

    half8 a[2][2];
#pragma unroll
    for (int rf = 0; rf < 2; ++rf) {
        const float* xrow = X + (size_t)(wrow + rf * 16 + c4) * D;
#pragma unroll
        for (int f = 0; f < 2; ++f) {
            float4 lo = *(const float4*)(xrow + f * 32 + kg * 8);
            float4 hi = *(const float4*)(xrow + f * 32 + kg * 8 + 4);
            half8 h;
            h[0] = (_Float16)lo.x; h[1] = (_Float16)lo.y;
            h[2] = (_Float16)lo.z; h[3] = (_Float16)lo.w;
            h[4] = (_Float16)hi.x; h[5] = (_Float16)hi.y;
            h[6] = (_Float16)hi.z; h[7] = (_Float16)hi.w;
            a[rf][f] = h;
        }
    }

    float m1[2][4], m2[2][4];
    unsigned gid[2][4];
#pragma unroll
    for (int rf = 0; rf < 2; ++rf)
#pragma unroll
        for (int r = 0; r < 4; ++r) {
            m1[rf][r] = 3.4e38f;
            m2[rf][r] = 3.4e38f;
            gid[rf][r] = 0;
        }

#define STAGE(BUF, CH)                                                        \
    {                                                                         \
        _Pragma("unroll") for (int it = 0; it < 2; ++it) {                    \
            int q = it * 512 + tid;                                           \
            int c = q >> 3, p = q & 7, j = p ^ (c & 7);                       \
            const _Float16* src =                                             \
                Ef16 + ((size_t)((CH)*128 + c) * D + j * 8);                  \
            __builtin_amdgcn_global_load_lds((gas_t*)src,                     \
                                             (las_t*)&els[BUF][q * 8], 16, 0, \
                                             0);                              \
        }                                                                     \
        if (tid < 32) {                                                       \
            const float* s2 = e2 + (CH)*128 + tid * 4;                        \
            __builtin_amdgcn_global_load_lds(                                 \
                (gas_t*)s2, (las_t*)&e2ls[BUF][tid * 4], 16, 0, 0);           \
        }                                                                     \
    }

    STAGE(0, 0)

    for (int ch = 0; ch < 64; ++ch) {
        __syncthreads();
        if (ch < 63) STAGE((ch + 1) & 1, ch + 1)
        const int buf = ch & 1;

#pragma unroll
        for (int pb = 0; pb < 4; ++pb) {
            const int c0 = pb * 32 + c4;
            const int c1 = pb * 32 + 16 + c4;
            const int sw = c4 & 7;
            half8 b00 = *(const half8*)&els[buf][c0 * 64 + ((0 + kg) ^ sw) * 8];
            half8 b01 = *(const half8*)&els[buf][c0 * 64 + ((4 + kg) ^ sw) * 8];
            half8 b10 = *(const half8*)&els[buf][c1 * 64 + ((0 + kg) ^ sw) * 8];
            half8 b11 = *(const half8*)&els[buf][c1 * 64 + ((4 + kg) ^ sw) * 8];
            float e2v0 = e2ls[buf][pb * 32 + c4];
            float e2v1 = e2ls[buf][pb * 32 + 16 + c4];
            f32x4 i0 = {e2v0, e2v0, e2v0, e2v0};
            f32x4 i1 = {e2v1, e2v1, e2v1, e2v1};

            f32x4 acc[2][2];
#pragma unroll
            for (int rf = 0; rf < 2; ++rf) {
                f32x4 t0 = __builtin_amdgcn_mfma_f32_16x16x32_f16(a[rf][0], b00, i0, 0, 0, 0);
                acc[rf][0] = __builtin_amdgcn_mfma_f32_16x16x32_f16(a[rf][1], b01, t0, 0, 0, 0);
                f32x4 t1 = __builtin_amdgcn_mfma_f32_16x16x32_f16(a[rf][0], b10, i1, 0, 0, 0);
                acc[rf][1] = __builtin_amdgcn_mfma_f32_16x16x32_f16(a[rf][1], b11, t1, 0, 0, 0);
            }

            const unsigned pid = (unsigned)(ch * 4 + pb);
#pragma unroll
            for (int rf = 0; rf < 2; ++rf)
#pragma unroll
                for (int r = 0; r < 4; ++r) {
                    float v0 = acc[rf][0][r], v1 = acc[rf][1][r];
                    float a1 = fminf(v0, v1);
                    float a2 = fmaxf(v0, v1);
                    float om1 = m1[rf][r];
                    m2[rf][r] = fminf(fminf(fmaxf(om1, a1), m2[rf][r]), a2);
                    if (a1 < om1) gid[rf][r] = pid;
                    m1[rf][r] = fminf(om1, a1);
                }
        }
    }

#pragma unroll
    for (int rf = 0; rf < 2; ++rf)
#pragma unroll
        for (int r = 0; r < 4; ++r) {
            float v1 = m1[rf][r], v2 = m2[rf][r];
            unsigned g = gid[rf][r];
#pragma unroll
            for (int off = 1; off < 16; off <<= 1) {
                float o1 = __shfl_xor(v1, off, 16);
                float o2 = __shfl_xor(v2, off, 16);
                unsigned og = __shfl_xor((int)g, off, 16);
                v2 = fminf(fminf(fmaxf(v1, o1), v2), o2);
                if (o1 < v1) { g = og; }
                v1 = fminf(v1, o1);
            }
            if (c4 == 0) {
                int row = wrow + rf * 16 + kg * 4 + r;
                unsigned flag = (v2 - v1 < MARGIN) ? 1u : 0u;
                gidw[row] = (g << 1) | flag;
                if (flag) {
                    int p = atomicAdd(fcount, 1);
                    flist[p] = row;
                }
            }
        }
}

// ---------------- kernel 3: exact group scan for UNFLAGGED rows -------------
// one wave per row; lanes = 16 entries x 4 dim-groups; coalesced E reads.
__global__ __launch_bounds__(256) void k_group(const float* __restrict__ X,
                                               const float* __restrict__ E,
                                               const float* __restrict__ e2,
                                               const unsigned* __restrict__ gidw,
                                               float* __restrict__ dout) {
    const int lane = threadIdx.x & 63;
    const int row = blockIdx.x * 4 + (threadIdx.x >> 6);
    const unsigned g = gidw[row];
    if (g & 1) return;  // flagged rows handled by k_full (wave-uniform branch)

    const int e4 = lane >> 2;
    const int dg = lane & 3;
    const float4* xp = (const float4*)(X + (size_t)row * D) + dg * 4;
    float4 xa0 = xp[0], xa1 = xp[1], xa2 = xp[2], xa3 = xp[3];

    const int vbase = (int)(g >> 1) * 32;
    float best = 3.4e38f;
    int bidx = 0x7fffffff;
#pragma unroll
    for (int it = 0; it < 2; ++it) {
        int v = vbase + it * 16 + e4;
        const float4* ep = (const float4*)(E + (size_t)v * D) + dg * 4;
        float4 b0 = ep[0], b1 = ep[1], b2 = ep[2], b3 = ep[3];
        float s = 0.0f;
        DOT16(s, xa0, xa1, xa2, xa3, b0, b1, b2, b3)
        s += __shfl_xor(s, 1, 64);
        s += __shfl_xor(s, 2, 64);
        float d = fmaf(-2.0f, s, e2[v]);
        if (d < best) { best = d; bidx = v; }
    }
#pragma unroll
    for (int off = 4; off < 64; off <<= 1) {
        float ob = __shfl_xor(best, off, 64);
        int oi = __shfl_xor(bidx, off, 64);
        if (ob < best || (ob == best && oi < bidx)) { best = ob; bidx = oi; }
    }
    if (lane == 0) dout[IDX_OFF + row] = (float)bidx;
}

// ---------------- kernel 4: exact full scan for FLAGGED rows ----------------
// 2 rows per wave share each coalesced E sweep; early-exit past count.
__global__ __launch_bounds__(256) void k_full(const float* __restrict__ X,
                                              const float* __restrict__ E,
                                              const float* __restrict__ e2,
                                              const int* __restrict__ fcount,
                                              const int* __restrict__ flist,
                                              float* __restrict__ dout) {
    const int nf = *fcount;
    const int wid = blockIdx.x * 4 + (threadIdx.x >> 6);
    const int base = wid * 2;
    if (base >= nf) return;  // wave-uniform
    const int lane = threadIdx.x & 63;
    const int e4 = lane >> 2;
    const int dg = lane & 3;

    const int r0 = flist[base];
    const int r1 = (base + 1 < nf) ? flist[base + 1] : r0;
    const float4* xp0 = (const float4*)(X + (size_t)r0 * D) + dg * 4;
    const float4* xp1 = (const float4*)(X + (size_t)r1 * D) + dg * 4;
    float4 xa0 = xp0[0], xa1 = xp0[1], xa2 = xp0[2], xa3 = xp0[3];
    float4 xb0 = xp1[0], xb1 = xp1[1], xb2 = xp1[2], xb3 = xp1[3];

    float best0 = 3.4e38f, best1 = 3.4e38f;
    int bi0 = 0x7fffffff, bi1 = 0x7fffffff;

    for (int v0 = 0; v0 < V; v0 += 16) {
        const int v = v0 + e4;
        const float4* ep = (const float4*)(E + (size_t)v * D) + dg * 4;
        float4 b0 = ep[0], b1 = ep[1], b2 = ep[2], b3 = ep[3];
        float s0 = 0.0f, s1 = 0.0f;
        DOT16(s0, xa0, xa1, xa2, xa3, b0, b1, b2, b3)
        DOT16(s1, xb0, xb1, xb2, xb3, b0, b1, b2, b3)
        s0 += __shfl_xor(s0, 1, 64);
        s0 += __shfl_xor(s0, 2, 64);
        s1 += __shfl_xor(s1, 1, 64);
        s1 += __shfl_xor(s1, 2, 64);
        const float ev = e2[v];
        float d0 = fmaf(-2.0f, s0, ev);
        float d1 = fmaf(-2.0f, s1, ev);
        if (d0 < best0) { best0 = d0; bi0 = v; }
        if (d1 < best1) { best1 = d1; bi1 = v; }
    }
#pragma unroll
    for (int off = 4; off < 64; off <<= 1) {
        float ob = __shfl_xor(best0, off, 64);
        int oi = __shfl_xor(bi0, off, 64);
        if (ob < best0 || (ob == best0 && oi < bi0)) { best0 = ob; bi0 = oi; }
        float ob1 = __shfl_xor(best1, off, 64);
        int oi1 = __shfl_xor(bi1, off, 64);
        if (ob1 < best1 || (ob1 == best1 && oi1 < bi1)) { best1 = ob1; bi1 = oi1; }
    }
    if (lane == 0) {
        dout[IDX_OFF + r0] = (float)bi0;
        if (base + 1 < nf) dout[IDX_OFF + r1] = (float)bi1;
    }
}

// ---------------- kernel 5: gather + STE output + loss ----------------------
__global__ void k_out(const float* __restrict__ X, const float* __restrict__ E,
                      float* __restrict__ dout) {
    const int t = blockIdx.x * 256 + threadIdx.x;
    const int n = t >> 4;
    const int d = (t & 15) * 4;
    const int idx = (int)dout[IDX_OFF + n];
    float4 x4 = *(const float4*)(X + (size_t)n * D + d);
    float4 q4 = *(const float4*)(E + (size_t)idx * D + d);
    float4 o;
    o.x = x4.x + (q4.x - x4.x);
    o.y = x4.y + (q4.y - x4.y);
    o.z = x4.z + (q4.z - x4.z);
    o.w = x4.w + (q4.w - x4.w);
    *(float4*)(dout + (size_t)n * D + d) = o;

    float dx = q4.x - x4.x, dy = q4.y - x4.y, dz = q4.z - x4.z,
          dw = q4.w - x4.w;
    float s = dx * dx + dy * dy + dz * dz + dw * dw;
#pragma unroll
    for (int off = 32; off; off >>= 1) s += __shfl_down(s, off, 64);
    __shared__ float ps[4];
    if ((threadIdx.x & 63) == 0) ps[threadIdx.x >> 6] = s;
    __syncthreads();
    if (threadIdx.x == 0) {
        float tot = ps[0] + ps[1] + ps[2] + ps[3];
        atomicAdd(dout + LOSS_OFF, tot * (1.25f / ((float)N * (float)D)));
    }
}

extern "C" void kernel_launch(void* const* d_in, const int* in_sizes, int n_in,
                              void* d_out, int out_size, void* d_ws,
                              size_t ws_size, hipStream_t stream) {
    const float* X = (const float*)d_in[0];
    const float* E = (const float*)d_in[1];
    float* out = (float*)d_out;

    char* ws = (char*)d_ws;
    _Float16* Ef16 = (_Float16*)ws;                       // 1 MB
    float* e2 = (float*)(ws + (1 << 20));                 // 32 KB
    unsigned* gidw = (unsigned*)(ws + (1 << 20) + (32 << 10));   // 256 KB
    int* fcount = (int*)(ws + (1 << 20) + (32 << 10) + (256 << 10));  // 256 B
    int* flist = fcount + 64;                             // 256 KB

    k_split<<<V / 256, 256, 0, stream>>>(E, Ef16, e2, out, fcount);
    k_argmin<<<N / 256, 512, 0, stream>>>(X, Ef16, e2, gidw, fcount, flist);
    k_group<<<N / 4, 256, 0, stream>>>(X, E, e2, gidw, out);
    k_full<<<8192, 256, 0, stream>>>(X, E, e2, fcount, flist, out);
    k_out<<<(N * 16) / 256, 256, 0, stream>>>(X, E, out);
}

// Round 4
// 306.170 us; speedup vs baseline: 3.8012x; 1.3878x over previous
//
#include <hip/hip_runtime.h>

#define N 65536
#define D 64
#define V 8192
#define LOSS_OFF (N * D)
#define IDX_OFF (N * D + 1)
#define MARGIN 0.02f

typedef _Float16 half8 __attribute__((ext_vector_type(8)));
typedef float f32x4 __attribute__((ext_vector_type(4)));

typedef __attribute__((address_space(1))) const void gas_t;
typedef __attribute__((address_space(3))) void las_t;

// 16-dim partial dot with named float4 regs (never an indexed array -> no scratch)
#define DOT16(s, A0, A1, A2, A3, B0, B1, B2, B3)                         \
    s = fmaf(A0.x, B0.x, s); s = fmaf(A0.y, B0.y, s);                    \
    s = fmaf(A0.z, B0.z, s); s = fmaf(A0.w, B0.w, s);                    \
    s = fmaf(A1.x, B1.x, s); s = fmaf(A1.y, B1.y, s);                    \
    s = fmaf(A1.z, B1.z, s); s = fmaf(A1.w, B1.w, s);                    \
    s = fmaf(A2.x, B2.x, s); s = fmaf(A2.y, B2.y, s);                    \
    s = fmaf(A2.z, B2.z, s); s = fmaf(A2.w, B2.w, s);                    \
    s = fmaf(A3.x, B3.x, s); s = fmaf(A3.y, B3.y, s);                    \
    s = fmaf(A3.z, B3.z, s); s = fmaf(A3.w, B3.w, s);

// order-preserving f32 -> u32 (finite values): min score == min encoding
__device__ __forceinline__ unsigned enc32(float f) {
    unsigned u = __float_as_uint(f);
    return (u & 0x80000000u) ? ~u : (u | 0x80000000u);
}

// ---------------- kernel 1: Ef16 = f16(-2E), e2 = sum E^2, zero scalars -----
__global__ void k_split(const float* __restrict__ E, _Float16* __restrict__ Ef16,
                        float* __restrict__ e2, float* __restrict__ dout,
                        int* __restrict__ fcount) {
    int v = blockIdx.x * 256 + threadIdx.x;
    if (v == 0) {
        dout[LOSS_OFF] = 0.0f;
        *fcount = 0;
    }
    if (v >= V) return;
    const float4* row = (const float4*)(E + (size_t)v * D);
    float s = 0.0f;
#pragma unroll
    for (int i = 0; i < 16; ++i) {
        float4 t = row[i];
        s += t.x * t.x + t.y * t.y + t.z * t.z + t.w * t.w;
    }
    e2[v] = s;
#pragma unroll
    for (int i = 0; i < 8; ++i) {
        float4 lo = row[i * 2];
        float4 hi = row[i * 2 + 1];
        half8 h;
        h[0] = (_Float16)(-2.0f * lo.x); h[1] = (_Float16)(-2.0f * lo.y);
        h[2] = (_Float16)(-2.0f * lo.z); h[3] = (_Float16)(-2.0f * lo.w);
        h[4] = (_Float16)(-2.0f * hi.x); h[5] = (_Float16)(-2.0f * hi.y);
        h[6] = (_Float16)(-2.0f * hi.z); h[7] = (_Float16)(-2.0f * hi.w);
        *(half8*)(Ef16 + (size_t)v * D + i * 8) = h;
    }
}

// ---------------- kernel 2: MFMA approx argmin + flagged-row compaction -----
__global__ __launch_bounds__(512) void k_argmin(const float* __restrict__ X,
                                                const _Float16* __restrict__ Ef16,
                                                const float* __restrict__ e2,
                                                unsigned* __restrict__ gidw,
                                                int* __restrict__ fcount,
                                                int* __restrict__ flist,
                                                unsigned long long* __restrict__ packed) {
    __shared__ __align__(16) _Float16 els[2][8192];  // 2 x 16KB, swizzled
    __shared__ __align__(16) float e2ls[2][128];

    const int tid = threadIdx.x;
    const int lane = tid & 63;
    const int wave = tid >> 6;
    const int c4 = lane & 15;
    const int kg = lane >> 4;  // 0..3
    const int wrow = blockIdx.x * 256 + wave * 32;

    half8 a[2][2];
#pragma unroll
    for (int rf = 0; rf < 2; ++rf) {
        const float* xrow = X + (size_t)(wrow + rf * 16 + c4) * D;
#pragma unroll
        for (int f = 0; f < 2; ++f) {
            float4 lo = *(const float4*)(xrow + f * 32 + kg * 8);
            float4 hi = *(const float4*)(xrow + f * 32 + kg * 8 + 4);
            half8 h;
            h[0] = (_Float16)lo.x; h[1] = (_Float16)lo.y;
            h[2] = (_Float16)lo.z; h[3] = (_Float16)lo.w;
            h[4] = (_Float16)hi.x; h[5] = (_Float16)hi.y;
            h[6] = (_Float16)hi.z; h[7] = (_Float16)hi.w;
            a[rf][f] = h;
        }
    }

    float m1[2][4], m2[2][4];
    unsigned gid[2][4];
#pragma unroll
    for (int rf = 0; rf < 2; ++rf)
#pragma unroll
        for (int r = 0; r < 4; ++r) {
            m1[rf][r] = 3.4e38f;
            m2[rf][r] = 3.4e38f;
            gid[rf][r] = 0;
        }

#define STAGE(BUF, CH)                                                        \
    {                                                                         \
        _Pragma("unroll") for (int it = 0; it < 2; ++it) {                    \
            int q = it * 512 + tid;                                           \
            int c = q >> 3, p = q & 7, j = p ^ (c & 7);                       \
            const _Float16* src =                                             \
                Ef16 + ((size_t)((CH)*128 + c) * D + j * 8);                  \
            __builtin_amdgcn_global_load_lds((gas_t*)src,                     \
                                             (las_t*)&els[BUF][q * 8], 16, 0, \
                                             0);                              \
        }                                                                     \
        if (tid < 32) {                                                       \
            const float* s2 = e2 + (CH)*128 + tid * 4;                        \
            __builtin_amdgcn_global_load_lds(                                 \
                (gas_t*)s2, (las_t*)&e2ls[BUF][tid * 4], 16, 0, 0);           \
        }                                                                     \
    }

    STAGE(0, 0)

    for (int ch = 0; ch < 64; ++ch) {
        __syncthreads();
        if (ch < 63) STAGE((ch + 1) & 1, ch + 1)
        const int buf = ch & 1;

#pragma unroll
        for (int pb = 0; pb < 4; ++pb) {
            const int c0 = pb * 32 + c4;
            const int c1 = pb * 32 + 16 + c4;
            const int sw = c4 & 7;
            half8 b00 = *(const half8*)&els[buf][c0 * 64 + ((0 + kg) ^ sw) * 8];
            half8 b01 = *(const half8*)&els[buf][c0 * 64 + ((4 + kg) ^ sw) * 8];
            half8 b10 = *(const half8*)&els[buf][c1 * 64 + ((0 + kg) ^ sw) * 8];
            half8 b11 = *(const half8*)&els[buf][c1 * 64 + ((4 + kg) ^ sw) * 8];
            float e2v0 = e2ls[buf][pb * 32 + c4];
            float e2v1 = e2ls[buf][pb * 32 + 16 + c4];
            f32x4 i0 = {e2v0, e2v0, e2v0, e2v0};
            f32x4 i1 = {e2v1, e2v1, e2v1, e2v1};

            f32x4 acc[2][2];
#pragma unroll
            for (int rf = 0; rf < 2; ++rf) {
                f32x4 t0 = __builtin_amdgcn_mfma_f32_16x16x32_f16(a[rf][0], b00, i0, 0, 0, 0);
                acc[rf][0] = __builtin_amdgcn_mfma_f32_16x16x32_f16(a[rf][1], b01, t0, 0, 0, 0);
                f32x4 t1 = __builtin_amdgcn_mfma_f32_16x16x32_f16(a[rf][0], b10, i1, 0, 0, 0);
                acc[rf][1] = __builtin_amdgcn_mfma_f32_16x16x32_f16(a[rf][1], b11, t1, 0, 0, 0);
            }

            const unsigned pid = (unsigned)(ch * 4 + pb);
#pragma unroll
            for (int rf = 0; rf < 2; ++rf)
#pragma unroll
                for (int r = 0; r < 4; ++r) {
                    float v0 = acc[rf][0][r], v1 = acc[rf][1][r];
                    float a1 = fminf(v0, v1);
                    float a2 = fmaxf(v0, v1);
                    float om1 = m1[rf][r];
                    m2[rf][r] = fminf(fminf(fmaxf(om1, a1), m2[rf][r]), a2);
                    if (a1 < om1) gid[rf][r] = pid;
                    m1[rf][r] = fminf(om1, a1);
                }
        }
    }

#pragma unroll
    for (int rf = 0; rf < 2; ++rf)
#pragma unroll
        for (int r = 0; r < 4; ++r) {
            float v1 = m1[rf][r], v2 = m2[rf][r];
            unsigned g = gid[rf][r];
#pragma unroll
            for (int off = 1; off < 16; off <<= 1) {
                float o1 = __shfl_xor(v1, off, 16);
                float o2 = __shfl_xor(v2, off, 16);
                unsigned og = __shfl_xor((int)g, off, 16);
                v2 = fminf(fminf(fmaxf(v1, o1), v2), o2);
                if (o1 < v1) { g = og; }
                v1 = fminf(v1, o1);
            }
            if (c4 == 0) {
                int row = wrow + rf * 16 + kg * 4 + r;
                if (v2 - v1 < MARGIN) {
                    int p = atomicAdd(fcount, 1);
                    flist[p] = row;
                    packed[p] = ~0ull;
                    gidw[row] = ((unsigned)p << 1) | 1u;
                } else {
                    gidw[row] = (g << 1);
                }
            }
        }
}

// ---------------- kernel 3: exact group scan for UNFLAGGED rows -------------
__global__ __launch_bounds__(256) void k_group(const float* __restrict__ X,
                                               const float* __restrict__ E,
                                               const float* __restrict__ e2,
                                               const unsigned* __restrict__ gidw,
                                               float* __restrict__ dout) {
    const int lane = threadIdx.x & 63;
    const int row = blockIdx.x * 4 + (threadIdx.x >> 6);
    const unsigned g = gidw[row];
    if (g & 1) return;  // flagged rows handled by k_full (wave-uniform branch)

    const int e4 = lane >> 2;
    const int dg = lane & 3;
    const float4* xp = (const float4*)(X + (size_t)row * D) + dg * 4;
    float4 xa0 = xp[0], xa1 = xp[1], xa2 = xp[2], xa3 = xp[3];

    const int vbase = (int)(g >> 1) * 32;
    float best = 3.4e38f;
    int bidx = 0x7fffffff;
#pragma unroll
    for (int it = 0; it < 2; ++it) {
        int v = vbase + it * 16 + e4;
        const float4* ep = (const float4*)(E + (size_t)v * D) + dg * 4;
        float4 b0 = ep[0], b1 = ep[1], b2 = ep[2], b3 = ep[3];
        float s = 0.0f;
        DOT16(s, xa0, xa1, xa2, xa3, b0, b1, b2, b3)
        s += __shfl_xor(s, 1, 64);
        s += __shfl_xor(s, 2, 64);
        float d = fmaf(-2.0f, s, e2[v]);
        if (d < best) { best = d; bidx = v; }
    }
#pragma unroll
    for (int off = 4; off < 64; off <<= 1) {
        float ob = __shfl_xor(best, off, 64);
        int oi = __shfl_xor(bidx, off, 64);
        if (ob < best || (ob == best && oi < bidx)) { best = ob; bidx = oi; }
    }
    if (lane == 0) dout[IDX_OFF + row] = (float)bidx;
}

// ---------------- kernel 4: exact full scan for FLAGGED rows ----------------
// work item = (row-quad, 1/8 chunk of V); grid-stride; atomicMin u64 merge.
__global__ __launch_bounds__(256) void k_full(const float* __restrict__ X,
                                              const float* __restrict__ E,
                                              const float* __restrict__ e2,
                                              const int* __restrict__ fcount,
                                              const int* __restrict__ flist,
                                              unsigned long long* __restrict__ packed) {
    const int nf = *fcount;
    if (nf == 0) return;
    const int nq = (nf + 3) >> 2;
    const int total = nq * 8;
    const int lane = threadIdx.x & 63;
    const int nwaves = gridDim.x * 4;
    int item = blockIdx.x * 4 + (threadIdx.x >> 6);
    const int e4 = lane >> 2;
    const int dg = lane & 3;

    for (; item < total; item += nwaves) {
        const int qi = item >> 3;
        const int c = item & 7;
        const int f0 = qi * 4;
        const int f1 = min(f0 + 1, nf - 1);
        const int f2 = min(f0 + 2, nf - 1);
        const int f3 = min(f0 + 3, nf - 1);
        const int r0 = flist[f0], r1 = flist[f1], r2 = flist[f2], r3 = flist[f3];

        const float4* xp0 = (const float4*)(X + (size_t)r0 * D) + dg * 4;
        const float4* xp1 = (const float4*)(X + (size_t)r1 * D) + dg * 4;
        const float4* xp2 = (const float4*)(X + (size_t)r2 * D) + dg * 4;
        const float4* xp3 = (const float4*)(X + (size_t)r3 * D) + dg * 4;
        float4 xa0 = xp0[0], xa1 = xp0[1], xa2 = xp0[2], xa3 = xp0[3];
        float4 xb0 = xp1[0], xb1 = xp1[1], xb2 = xp1[2], xb3 = xp1[3];
        float4 xc0 = xp2[0], xc1 = xp2[1], xc2 = xp2[2], xc3 = xp2[3];
        float4 xd0 = xp3[0], xd1 = xp3[1], xd2 = xp3[2], xd3 = xp3[3];

        unsigned long long k0 = ~0ull, k1 = ~0ull, k2 = ~0ull, k3 = ~0ull;

#pragma unroll 2
        for (int it = 0; it < 64; ++it) {
            const int v = c * 1024 + it * 16 + e4;
            const float4* ep = (const float4*)(E + (size_t)v * D) + dg * 4;
            float4 b0 = ep[0], b1 = ep[1], b2 = ep[2], b3 = ep[3];
            float s0 = 0.0f, s1 = 0.0f, s2 = 0.0f, s3 = 0.0f;
            DOT16(s0, xa0, xa1, xa2, xa3, b0, b1, b2, b3)
            DOT16(s1, xb0, xb1, xb2, xb3, b0, b1, b2, b3)
            DOT16(s2, xc0, xc1, xc2, xc3, b0, b1, b2, b3)
            DOT16(s3, xd0, xd1, xd2, xd3, b0, b1, b2, b3)
            s0 += __shfl_xor(s0, 1, 64); s0 += __shfl_xor(s0, 2, 64);
            s1 += __shfl_xor(s1, 1, 64); s1 += __shfl_xor(s1, 2, 64);
            s2 += __shfl_xor(s2, 1, 64); s2 += __shfl_xor(s2, 2, 64);
            s3 += __shfl_xor(s3, 1, 64); s3 += __shfl_xor(s3, 2, 64);
            const float ev = e2[v];
            const unsigned long long vb = (unsigned long long)(unsigned)v;
            unsigned long long t;
            t = ((unsigned long long)enc32(fmaf(-2.0f, s0, ev)) << 32) | vb;
            k0 = t < k0 ? t : k0;
            t = ((unsigned long long)enc32(fmaf(-2.0f, s1, ev)) << 32) | vb;
            k1 = t < k1 ? t : k1;
            t = ((unsigned long long)enc32(fmaf(-2.0f, s2, ev)) << 32) | vb;
            k2 = t < k2 ? t : k2;
            t = ((unsigned long long)enc32(fmaf(-2.0f, s3, ev)) << 32) | vb;
            k3 = t < k3 ? t : k3;
        }

#pragma unroll
        for (int off = 4; off < 64; off <<= 1) {
            unsigned lo, hi;
            unsigned long long o;
            lo = __shfl_xor((unsigned)k0, off, 64); hi = __shfl_xor((unsigned)(k0 >> 32), off, 64);
            o = ((unsigned long long)hi << 32) | lo; k0 = o < k0 ? o : k0;
            lo = __shfl_xor((unsigned)k1, off, 64); hi = __shfl_xor((unsigned)(k1 >> 32), off, 64);
            o = ((unsigned long long)hi << 32) | lo; k1 = o < k1 ? o : k1;
            lo = __shfl_xor((unsigned)k2, off, 64); hi = __shfl_xor((unsigned)(k2 >> 32), off, 64);
            o = ((unsigned long long)hi << 32) | lo; k2 = o < k2 ? o : k2;
            lo = __shfl_xor((unsigned)k3, off, 64); hi = __shfl_xor((unsigned)(k3 >> 32), off, 64);
            o = ((unsigned long long)hi << 32) | lo; k3 = o < k3 ? o : k3;
        }

        if (lane == 0) {
            atomicMin(&packed[f0], k0);
            atomicMin(&packed[f1], k1);
            atomicMin(&packed[f2], k2);
            atomicMin(&packed[f3], k3);
        }
    }
}

// ---------------- kernel 5: gather + STE output + loss ----------------------
__global__ void k_out(const float* __restrict__ X, const float* __restrict__ E,
                      const unsigned* __restrict__ gidw,
                      const unsigned long long* __restrict__ packed,
                      float* __restrict__ dout) {
    const int t = blockIdx.x * 256 + threadIdx.x;
    const int n = t >> 4;
    const int d = (t & 15) * 4;
    const unsigned g = gidw[n];
    int idx;
    if (g & 1) {
        idx = (int)(unsigned)(packed[g >> 1] & 0xffffffffull);
        if (d == 0) dout[IDX_OFF + n] = (float)idx;
    } else {
        idx = (int)dout[IDX_OFF + n];
    }
    float4 x4 = *(const float4*)(X + (size_t)n * D + d);
    float4 q4 = *(const float4*)(E + (size_t)idx * D + d);
    float4 o;
    o.x = x4.x + (q4.x - x4.x);
    o.y = x4.y + (q4.y - x4.y);
    o.z = x4.z + (q4.z - x4.z);
    o.w = x4.w + (q4.w - x4.w);
    *(float4*)(dout + (size_t)n * D + d) = o;

    float dx = q4.x - x4.x, dy = q4.y - x4.y, dz = q4.z - x4.z,
          dw = q4.w - x4.w;
    float s = dx * dx + dy * dy + dz * dz + dw * dw;
#pragma unroll
    for (int off = 32; off; off >>= 1) s += __shfl_down(s, off, 64);
    __shared__ float ps[4];
    if ((threadIdx.x & 63) == 0) ps[threadIdx.x >> 6] = s;
    __syncthreads();
    if (threadIdx.x == 0) {
        float tot = ps[0] + ps[1] + ps[2] + ps[3];
        atomicAdd(dout + LOSS_OFF, tot * (1.25f / ((float)N * (float)D)));
    }
}

extern "C" void kernel_launch(void* const* d_in, const int* in_sizes, int n_in,
                              void* d_out, int out_size, void* d_ws,
                              size_t ws_size, hipStream_t stream) {
    const float* X = (const float*)d_in[0];
    const float* E = (const float*)d_in[1];
    float* out = (float*)d_out;

    char* ws = (char*)d_ws;
    _Float16* Ef16 = (_Float16*)ws;                                   // 1 MB
    float* e2 = (float*)(ws + 1048576);                               // 32 KB
    unsigned* gidw = (unsigned*)(ws + 1081344);                       // 256 KB
    int* fcount = (int*)(ws + 1343488);                               // 256 B
    int* flist = (int*)(ws + 1343744);                                // 256 KB
    unsigned long long* packed = (unsigned long long*)(ws + 1605888); // 512 KB

    k_split<<<V / 256, 256, 0, stream>>>(E, Ef16, e2, out, fcount);
    k_argmin<<<N / 256, 512, 0, stream>>>(X, Ef16, e2, gidw, fcount, flist, packed);
    k_group<<<N / 4, 256, 0, stream>>>(X, E, e2, gidw, out);
    k_full<<<1024, 256, 0, stream>>>(X, E, e2, fcount, flist, packed);
    k_out<<<(N * 16) / 256, 256, 0, stream>>>(X, E, gidw, packed, out);
}

// Round 5
// 245.663 us; speedup vs baseline: 4.7374x; 1.2463x over previous
//
#include <hip/hip_runtime.h>

#define N 65536
#define D 64
#define V 8192
#define LOSS_OFF (N * D)
#define IDX_OFF (N * D + 1)
#define MARGIN 0.02f

typedef _Float16 half8 __attribute__((ext_vector_type(8)));
typedef float f32x4 __attribute__((ext_vector_type(4)));

typedef __attribute__((address_space(1))) const void gas_t;
typedef __attribute__((address_space(3))) void las_t;

// 16-dim partial dot with named float4 regs (never an indexed array -> no scratch)
#define DOT16(s, A0, A1, A2, A3, B0, B1, B2, B3)                         \
    s = fmaf(A0.x, B0.x, s); s = fmaf(A0.y, B0.y, s);                    \
    s = fmaf(A0.z, B0.z, s); s = fmaf(A0.w, B0.w, s);                    \
    s = fmaf(A1.x, B1.x, s); s = fmaf(A1.y, B1.y, s);                    \
    s = fmaf(A1.z, B1.z, s); s = fmaf(A1.w, B1.w, s);                    \
    s = fmaf(A2.x, B2.x, s); s = fmaf(A2.y, B2.y, s);                    \
    s = fmaf(A2.z, B2.z, s); s = fmaf(A2.w, B2.w, s);                    \
    s = fmaf(A3.x, B3.x, s); s = fmaf(A3.y, B3.y, s);                    \
    s = fmaf(A3.z, B3.z, s); s = fmaf(A3.w, B3.w, s);

// order-preserving f32 -> u32 (finite values): min score == min encoding
__device__ __forceinline__ unsigned enc32(float f) {
    unsigned u = __float_as_uint(f);
    return (u & 0x80000000u) ? ~u : (u | 0x80000000u);
}

// ---------------- kernel 1: Ef16 = f16(-2E), e2 = sum E^2, zero scalars -----
__global__ void k_split(const float* __restrict__ E, _Float16* __restrict__ Ef16,
                        float* __restrict__ e2, float* __restrict__ dout,
                        int* __restrict__ fcount) {
    int v = blockIdx.x * 256 + threadIdx.x;
    if (v == 0) {
        dout[LOSS_OFF] = 0.0f;
        *fcount = 0;
    }
    if (v >= V) return;
    const float4* row = (const float4*)(E + (size_t)v * D);
    float s = 0.0f;
#pragma unroll
    for (int i = 0; i < 16; ++i) {
        float4 t = row[i];
        s += t.x * t.x + t.y * t.y + t.z * t.z + t.w * t.w;
    }
    e2[v] = s;
#pragma unroll
    for (int i = 0; i < 8; ++i) {
        float4 lo = row[i * 2];
        float4 hi = row[i * 2 + 1];
        half8 h;
        h[0] = (_Float16)(-2.0f * lo.x); h[1] = (_Float16)(-2.0f * lo.y);
        h[2] = (_Float16)(-2.0f * lo.z); h[3] = (_Float16)(-2.0f * lo.w);
        h[4] = (_Float16)(-2.0f * hi.x); h[5] = (_Float16)(-2.0f * hi.y);
        h[6] = (_Float16)(-2.0f * hi.z); h[7] = (_Float16)(-2.0f * hi.w);
        *(half8*)(Ef16 + (size_t)v * D + i * 8) = h;
    }
}

// ---------------- kernel 2: MFMA approx argmin, entry-major accumulators ----
// 256 thr = 4 waves; each wave owns 32 x-rows (2 B-frags). A = E-tile (16
// entries), B = X. acc f32x4 = 4 consecutive entries of one x-row; e2 quad is
// the MFMA C-init (exact f32). Leaf = 16 entries; track (m1, m2, leaf-id).
#define MERGE(M1, M2, GID, L, PID)          \
    {                                       \
        bool bt = (L) < (M1);               \
        float m2c = bt ? (M1) : (L);        \
        (M2) = fminf((M2), m2c);            \
        (GID) = bt ? (PID) : (GID);         \
        (M1) = fminf((M1), (L));            \
    }

__global__ __launch_bounds__(256) void k_argmin(const float* __restrict__ X,
                                                const _Float16* __restrict__ Ef16,
                                                const float* __restrict__ e2,
                                                unsigned* __restrict__ gidw,
                                                int* __restrict__ fcount,
                                                int* __restrict__ flist,
                                                unsigned long long* __restrict__ packed) {
    __shared__ __align__(16) _Float16 els[2][8192];  // 2 x 16KB, swizzled
    __shared__ __align__(16) float e2ls[2][128];

    const int tid = threadIdx.x;
    const int lane = tid & 63;
    const int wave = tid >> 6;
    const int c4 = lane & 15;   // A-row slot / B-col slot (x-row within frag)
    const int kg = lane >> 4;   // K-slice 0..3
    const int wrow = blockIdx.x * 128 + wave * 32;
    const int sw = c4 & 7;
    const int k0off = (kg ^ sw) * 8;        // dims 0..31 subchunk
    const int k1off = ((4 + kg) ^ sw) * 8;  // dims 32..63 subchunk

    // B-frags: X rows (loop-invariant registers)
    half8 x00, x01, x10, x11;
    {
        const float* xr0 = X + (size_t)(wrow + c4) * D;
        const float* xr1 = X + (size_t)(wrow + 16 + c4) * D;
#pragma unroll
        for (int f = 0; f < 2; ++f) {
            float4 lo = *(const float4*)(xr0 + f * 32 + kg * 8);
            float4 hi = *(const float4*)(xr0 + f * 32 + kg * 8 + 4);
            half8 h;
            h[0] = (_Float16)lo.x; h[1] = (_Float16)lo.y;
            h[2] = (_Float16)lo.z; h[3] = (_Float16)lo.w;
            h[4] = (_Float16)hi.x; h[5] = (_Float16)hi.y;
            h[6] = (_Float16)hi.z; h[7] = (_Float16)hi.w;
            if (f == 0) x00 = h; else x01 = h;
        }
#pragma unroll
        for (int f = 0; f < 2; ++f) {
            float4 lo = *(const float4*)(xr1 + f * 32 + kg * 8);
            float4 hi = *(const float4*)(xr1 + f * 32 + kg * 8 + 4);
            half8 h;
            h[0] = (_Float16)lo.x; h[1] = (_Float16)lo.y;
            h[2] = (_Float16)lo.z; h[3] = (_Float16)lo.w;
            h[4] = (_Float16)hi.x; h[5] = (_Float16)hi.y;
            h[6] = (_Float16)hi.z; h[7] = (_Float16)hi.w;
            if (f == 0) x10 = h; else x11 = h;
        }
    }

    float m1a = 3.4e38f, m2a = 3.4e38f, m1b = 3.4e38f, m2b = 3.4e38f;
    unsigned gida = 0, gidb = 0;
    const unsigned kgu = (unsigned)kg;

#define STAGE(BUF, CH)                                                        \
    {                                                                         \
        _Pragma("unroll") for (int it = 0; it < 4; ++it) {                    \
            int q = it * 256 + tid;                                           \
            int c = q >> 3, p = q & 7, j = p ^ (c & 7);                       \
            const _Float16* src =                                             \
                Ef16 + ((size_t)((CH)*128 + c) * D + j * 8);                  \
            __builtin_amdgcn_global_load_lds((gas_t*)src,                     \
                                             (las_t*)&els[BUF][q * 8], 16, 0, \
                                             0);                              \
        }                                                                     \
        if (tid < 32) {                                                       \
            const float* s2 = e2 + (CH)*128 + tid * 4;                        \
            __builtin_amdgcn_global_load_lds(                                 \
                (gas_t*)s2, (las_t*)&e2ls[BUF][tid * 4], 16, 0, 0);           \
        }                                                                     \
    }

    STAGE(0, 0)

    for (int ch = 0; ch < 64; ++ch) {
        __syncthreads();  // drains prior STAGE (vmcnt) + protects buf reuse
        if (ch < 63) STAGE((ch + 1) & 1, ch + 1)
        const int buf = ch & 1;

        float La = 3.4e38f, Lb = 3.4e38f;
#pragma unroll
        for (int t = 0; t < 8; ++t) {
            const f32x4 e2q = *(const f32x4*)&e2ls[buf][t * 16 + kg * 4];
            const half8 a0 = *(const half8*)&els[buf][(t * 16 + c4) * 64 + k0off];
            const half8 a1 = *(const half8*)&els[buf][(t * 16 + c4) * 64 + k1off];

            f32x4 acc0 = __builtin_amdgcn_mfma_f32_16x16x32_f16(a0, x00, e2q, 0, 0, 0);
            acc0 = __builtin_amdgcn_mfma_f32_16x16x32_f16(a1, x01, acc0, 0, 0, 0);
            f32x4 acc1 = __builtin_amdgcn_mfma_f32_16x16x32_f16(a0, x10, e2q, 0, 0, 0);
            acc1 = __builtin_amdgcn_mfma_f32_16x16x32_f16(a1, x11, acc1, 0, 0, 0);

            La = fminf(fminf(La, fminf(acc0[0], acc0[1])), fminf(acc0[2], acc0[3]));
            Lb = fminf(fminf(Lb, fminf(acc1[0], acc1[1])), fminf(acc1[2], acc1[3]));

            if (t == 3 || t == 7) {
                unsigned pid = (unsigned)(ch * 8 + (t >> 2) * 4) + kgu;
                MERGE(m1a, m2a, gida, La, pid)
                MERGE(m1b, m2b, gidb, Lb, pid)
                La = 3.4e38f;
                Lb = 3.4e38f;
            }
        }
    }

    // merge the 4 kg lane-groups (lanes l, l+16, l+32, l+48 share an x-row)
#pragma unroll
    for (int off = 16; off < 64; off <<= 1) {
        float o1, o2;
        unsigned og;
        o1 = __shfl_xor(m1a, off, 64); o2 = __shfl_xor(m2a, off, 64);
        og = (unsigned)__shfl_xor((int)gida, off, 64);
        m2a = fminf(fminf(fmaxf(m1a, o1), m2a), o2);
        if (o1 < m1a) gida = og;
        m1a = fminf(m1a, o1);
        o1 = __shfl_xor(m1b, off, 64); o2 = __shfl_xor(m2b, off, 64);
        og = (unsigned)__shfl_xor((int)gidb, off, 64);
        m2b = fminf(fminf(fmaxf(m1b, o1), m2b), o2);
        if (o1 < m1b) gidb = og;
        m1b = fminf(m1b, o1);
    }

    if (lane < 16) {
        int row = wrow + lane;
        if (m2a - m1a < MARGIN) {
            int p = atomicAdd(fcount, 1);
            flist[p] = row;
            packed[p] = ~0ull;
            gidw[row] = ((unsigned)p << 1) | 1u;
        } else {
            gidw[row] = (gida << 1);
        }
        row = wrow + 16 + lane;
        if (m2b - m1b < MARGIN) {
            int p = atomicAdd(fcount, 1);
            flist[p] = row;
            packed[p] = ~0ull;
            gidw[row] = ((unsigned)p << 1) | 1u;
        } else {
            gidw[row] = (gidb << 1);
        }
    }
}

// ---------------- kernel 3: exact 16-entry leaf scan for UNFLAGGED rows -----
// leaf gid: entries = (g>>3)*128 + ((g>>2)&1)*64 + (e>>2)*16 + (g&3)*4 + (e&3)
__global__ __launch_bounds__(256) void k_group(const float* __restrict__ X,
                                               const float* __restrict__ E,
                                               const float* __restrict__ e2,
                                               const unsigned* __restrict__ gidw,
                                               float* __restrict__ dout) {
    const int lane = threadIdx.x & 63;
    const int row = blockIdx.x * 4 + (threadIdx.x >> 6);
    const unsigned g = gidw[row];
    if (g & 1) return;  // flagged rows handled by k_full (wave-uniform branch)
    const unsigned gg = g >> 1;

    const int e4 = lane >> 2;  // entry slot 0..15 (strictly increasing index)
    const int dg = lane & 3;
    const int v = (int)((gg >> 3) * 128 + ((gg >> 2) & 1) * 64 +
                        (e4 >> 2) * 16 + (gg & 3) * 4 + (e4 & 3));

    const float4* xp = (const float4*)(X + (size_t)row * D) + dg * 4;
    float4 xa0 = xp[0], xa1 = xp[1], xa2 = xp[2], xa3 = xp[3];
    const float4* ep = (const float4*)(E + (size_t)v * D) + dg * 4;
    float4 b0 = ep[0], b1 = ep[1], b2 = ep[2], b3 = ep[3];
    float s = 0.0f;
    DOT16(s, xa0, xa1, xa2, xa3, b0, b1, b2, b3)
    s += __shfl_xor(s, 1, 64);
    s += __shfl_xor(s, 2, 64);
    float best = fmaf(-2.0f, s, e2[v]);
    int bidx = v;
#pragma unroll
    for (int off = 4; off < 64; off <<= 1) {
        float ob = __shfl_xor(best, off, 64);
        int oi = __shfl_xor(bidx, off, 64);
        if (ob < best || (ob == best && oi < bidx)) { best = ob; bidx = oi; }
    }
    if (lane == 0) dout[IDX_OFF + row] = (float)bidx;
}

// ---------------- kernel 4: exact full scan for FLAGGED rows ----------------
__global__ __launch_bounds__(256) void k_full(const float* __restrict__ X,
                                              const float* __restrict__ E,
                                              const float* __restrict__ e2,
                                              const int* __restrict__ fcount,
                                              const int* __restrict__ flist,
                                              unsigned long long* __restrict__ packed) {
    const int nf = *fcount;
    if (nf == 0) return;
    const int nq = (nf + 3) >> 2;
    const int total = nq * 8;
    const int lane = threadIdx.x & 63;
    const int nwaves = gridDim.x * 4;
    int item = blockIdx.x * 4 + (threadIdx.x >> 6);
    const int e4 = lane >> 2;
    const int dg = lane & 3;

    for (; item < total; item += nwaves) {
        const int qi = item >> 3;
        const int c = item & 7;
        const int f0 = qi * 4;
        const int f1 = min(f0 + 1, nf - 1);
        const int f2 = min(f0 + 2, nf - 1);
        const int f3 = min(f0 + 3, nf - 1);
        const int r0 = flist[f0], r1 = flist[f1], r2 = flist[f2], r3 = flist[f3];

        const float4* xp0 = (const float4*)(X + (size_t)r0 * D) + dg * 4;
        const float4* xp1 = (const float4*)(X + (size_t)r1 * D) + dg * 4;
        const float4* xp2 = (const float4*)(X + (size_t)r2 * D) + dg * 4;
        const float4* xp3 = (const float4*)(X + (size_t)r3 * D) + dg * 4;
        float4 xa0 = xp0[0], xa1 = xp0[1], xa2 = xp0[2], xa3 = xp0[3];
        float4 xb0 = xp1[0], xb1 = xp1[1], xb2 = xp1[2], xb3 = xp1[3];
        float4 xc0 = xp2[0], xc1 = xp2[1], xc2 = xp2[2], xc3 = xp2[3];
        float4 xd0 = xp3[0], xd1 = xp3[1], xd2 = xp3[2], xd3 = xp3[3];

        unsigned long long k0 = ~0ull, k1 = ~0ull, k2 = ~0ull, k3 = ~0ull;

#pragma unroll 2
        for (int it = 0; it < 64; ++it) {
            const int v = c * 1024 + it * 16 + e4;
            const float4* ep = (const float4*)(E + (size_t)v * D) + dg * 4;
            float4 b0 = ep[0], b1 = ep[1], b2 = ep[2], b3 = ep[3];
            float s0 = 0.0f, s1 = 0.0f, s2 = 0.0f, s3 = 0.0f;
            DOT16(s0, xa0, xa1, xa2, xa3, b0, b1, b2, b3)
            DOT16(s1, xb0, xb1, xb2, xb3, b0, b1, b2, b3)
            DOT16(s2, xc0, xc1, xc2, xc3, b0, b1, b2, b3)
            DOT16(s3, xd0, xd1, xd2, xd3, b0, b1, b2, b3)
            s0 += __shfl_xor(s0, 1, 64); s0 += __shfl_xor(s0, 2, 64);
            s1 += __shfl_xor(s1, 1, 64); s1 += __shfl_xor(s1, 2, 64);
            s2 += __shfl_xor(s2, 1, 64); s2 += __shfl_xor(s2, 2, 64);
            s3 += __shfl_xor(s3, 1, 64); s3 += __shfl_xor(s3, 2, 64);
            const float ev = e2[v];
            const unsigned long long vb = (unsigned long long)(unsigned)v;
            unsigned long long t;
            t = ((unsigned long long)enc32(fmaf(-2.0f, s0, ev)) << 32) | vb;
            k0 = t < k0 ? t : k0;
            t = ((unsigned long long)enc32(fmaf(-2.0f, s1, ev)) << 32) | vb;
            k1 = t < k1 ? t : k1;
            t = ((unsigned long long)enc32(fmaf(-2.0f, s2, ev)) << 32) | vb;
            k2 = t < k2 ? t : k2;
            t = ((unsigned long long)enc32(fmaf(-2.0f, s3, ev)) << 32) | vb;
            k3 = t < k3 ? t : k3;
        }

#pragma unroll
        for (int off = 4; off < 64; off <<= 1) {
            unsigned lo, hi;
            unsigned long long o;
            lo = __shfl_xor((unsigned)k0, off, 64); hi = __shfl_xor((unsigned)(k0 >> 32), off, 64);
            o = ((unsigned long long)hi << 32) | lo; k0 = o < k0 ? o : k0;
            lo = __shfl_xor((unsigned)k1, off, 64); hi = __shfl_xor((unsigned)(k1 >> 32), off, 64);
            o = ((unsigned long long)hi << 32) | lo; k1 = o < k1 ? o : k1;
            lo = __shfl_xor((unsigned)k2, off, 64); hi = __shfl_xor((unsigned)(k2 >> 32), off, 64);
            o = ((unsigned long long)hi << 32) | lo; k2 = o < k2 ? o : k2;
            lo = __shfl_xor((unsigned)k3, off, 64); hi = __shfl_xor((unsigned)(k3 >> 32), off, 64);
            o = ((unsigned long long)hi << 32) | lo; k3 = o < k3 ? o : k3;
        }

        if (lane == 0) {
            atomicMin(&packed[f0], k0);
            atomicMin(&packed[f1], k1);
            atomicMin(&packed[f2], k2);
            atomicMin(&packed[f3], k3);
        }
    }
}

// ---------------- kernel 5: gather + STE output + loss ----------------------
__global__ void k_out(const float* __restrict__ X, const float* __restrict__ E,
                      const unsigned* __restrict__ gidw,
                      const unsigned long long* __restrict__ packed,
                      float* __restrict__ dout) {
    const int t = blockIdx.x * 256 + threadIdx.x;
    const int n = t >> 4;
    const int d = (t & 15) * 4;
    const unsigned g = gidw[n];
    int idx;
    if (g & 1) {
        idx = (int)(unsigned)(packed[g >> 1] & 0xffffffffull);
        if (d == 0) dout[IDX_OFF + n] = (float)idx;
    } else {
        idx = (int)dout[IDX_OFF + n];
    }
    float4 x4 = *(const float4*)(X + (size_t)n * D + d);
    float4 q4 = *(const float4*)(E + (size_t)idx * D + d);
    float4 o;
    o.x = x4.x + (q4.x - x4.x);
    o.y = x4.y + (q4.y - x4.y);
    o.z = x4.z + (q4.z - x4.z);
    o.w = x4.w + (q4.w - x4.w);
    *(float4*)(dout + (size_t)n * D + d) = o;

    float dx = q4.x - x4.x, dy = q4.y - x4.y, dz = q4.z - x4.z,
          dw = q4.w - x4.w;
    float s = dx * dx + dy * dy + dz * dz + dw * dw;
#pragma unroll
    for (int off = 32; off; off >>= 1) s += __shfl_down(s, off, 64);
    __shared__ float ps[4];
    if ((threadIdx.x & 63) == 0) ps[threadIdx.x >> 6] = s;
    __syncthreads();
    if (threadIdx.x == 0) {
        float tot = ps[0] + ps[1] + ps[2] + ps[3];
        atomicAdd(dout + LOSS_OFF, tot * (1.25f / ((float)N * (float)D)));
    }
}

extern "C" void kernel_launch(void* const* d_in, const int* in_sizes, int n_in,
                              void* d_out, int out_size, void* d_ws,
                              size_t ws_size, hipStream_t stream) {
    const float* X = (const float*)d_in[0];
    const float* E = (const float*)d_in[1];
    float* out = (float*)d_out;

    char* ws = (char*)d_ws;
    _Float16* Ef16 = (_Float16*)ws;                                   // 1 MB
    float* e2 = (float*)(ws + 1048576);                               // 32 KB
    unsigned* gidw = (unsigned*)(ws + 1081344);                       // 256 KB
    int* fcount = (int*)(ws + 1343488);                               // 256 B
    int* flist = (int*)(ws + 1343744);                                // 256 KB
    unsigned long long* packed = (unsigned long long*)(ws + 1605888); // 512 KB

    k_split<<<V / 256, 256, 0, stream>>>(E, Ef16, e2, out, fcount);
    k_argmin<<<N / 128, 256, 0, stream>>>(X, Ef16, e2, gidw, fcount, flist, packed);
    k_group<<<N / 4, 256, 0, stream>>>(X, E, e2, gidw, out);
    k_full<<<1024, 256, 0, stream>>>(X, E, e2, fcount, flist, packed);
    k_out<<<(N * 16) / 256, 256, 0, stream>>>(X, E, gidw, packed, out);
}